// Round 1
// baseline (47.456 us; speedup 1.0000x reference)
//
#include <hip/hip_runtime.h>
#include <hip/hip_bf16.h>

// Problem constants: B=8, T=128, n=127 neighbors, Q=K=64, H=4, O=H*K=256
#define NB 127
#define KD 64
#define OD 256

typedef __attribute__((ext_vector_type(8))) short bf16x8;
typedef __attribute__((ext_vector_type(4))) float f32x4;

__device__ __forceinline__ short bfs(float f) {
  __hip_bfloat16 h = __float2bfloat16(f);
  return __builtin_bit_cast(short, h);
}

// pack two floats -> two bf16 in one u32 (low = a); compiler fuses to v_cvt_pk_bf16_f32
__device__ __forceinline__ unsigned packbf2(float a, float b) {
  unsigned lo = (unsigned short)bfs(a);
  unsigned hi = (unsigned short)bfs(b);
  return lo | (hi << 16);
}

extern "C" __global__ void __launch_bounds__(256, 2)
rnn_attn_kernel(const float* __restrict__ q_x, const float* __restrict__ kv_x,
                const float* __restrict__ Wk, const float* __restrict__ Wq,
                const float* __restrict__ Wv, const float* __restrict__ bv,
                const float* __restrict__ bias, const float* __restrict__ wsc,
                float* __restrict__ out)
{
  // LDS: swizzled bf16 A-tile (128 rows x 64 bf16 = 128B/row) + small f32 arrays
  __shared__ __align__(16) unsigned char Atile[128 * 128];
  __shared__ float qx_s[64];
  __shared__ float ws_s[64];
  __shared__ float qqb_s[256];   // queries + bias, per o
  __shared__ float qv_s[256];    // q-part of values + bv, per o
  __shared__ float sc_s[128][4]; // score[n][h]
  __shared__ float wn_s[128][4]; // softmax weight[n][h]

  const int tid = threadIdx.x;
  const int bt = blockIdx.x;        // 0..1023 = b*128 + t
  const int lane = tid & 63;
  const int wv = tid >> 6;          // wave id == head id
  const int l15 = lane & 15;
  const int g = lane >> 4;

  // ---------------- Phase A: stage kv tile (127x64 f32 -> bf16 LDS, swizzled) ----
  const float* kv = kv_x + (size_t)bt * (NB * KD);
  #pragma unroll
  for (int i = 0; i < 8; ++i) {
    int idx = i * 256 + tid;        // float4-chunk index, 16 chunks per row
    if (idx < 2048) {
      int row = idx >> 4;
      int c = idx & 15;
      float4 v = (row < NB) ? ((const float4*)kv)[idx] : make_float4(0.f, 0.f, 0.f, 0.f);
      unsigned lo = packbf2(v.x, v.y);
      unsigned hi = packbf2(v.z, v.w);
      int byte = (row << 7) + (c << 3);
      byte ^= ((row & 7) << 4);     // XOR swizzle (G4): kills 16-way read conflict
      *(uint2*)(&Atile[byte]) = make_uint2(lo, hi);
    }
  }
  if (tid < 16)      ((float4*)qx_s)[tid]      = ((const float4*)(q_x + bt * 64))[tid];
  else if (tid < 32) ((float4*)ws_s)[tid - 16] = ((const float4*)wsc)[tid - 16];
  __syncthreads();

  // ---------------- Phase B: qqb[o] = q_x@Wq.T + bias ; qv[o] = q_x@Wv_q.T + bv ----
  {
    const int o = tid;
    float qq = 0.f, qvv = bv[o];
    const float4* wqr = (const float4*)(Wq + o * 64);
    const float4* wvr = (const float4*)(Wv + o * 128 + 64);
    const float4* qx4 = (const float4*)qx_s;
    #pragma unroll
    for (int i = 0; i < 16; ++i) {
      float4 a = wqr[i];
      float4 x = qx4[i];
      qq  = fmaf(a.x, x.x, fmaf(a.y, x.y, fmaf(a.z, x.z, fmaf(a.w, x.w, qq))));
      float4 b = wvr[i];
      qvv = fmaf(b.x, x.x, fmaf(b.y, x.y, fmaf(b.z, x.z, fmaf(b.w, x.w, qvv))));
    }
    qqb_s[o] = qq + bias[o & 63];
    qv_s[o] = qvv;
  }
  __syncthreads();

  const int obase = wv * 64;

  // ---------------- Phase C: keys GEMM (head wv) + tanh-score, fused per m-tile ----
  bf16x8 bfr[4][2];
  #pragma unroll
  for (int nt = 0; nt < 4; ++nt) {
    int o = obase + nt * 16 + l15;
    const float* wr = Wk + o * 64 + g * 8;
    #pragma unroll
    for (int kt = 0; kt < 2; ++kt) {
      float4 a = *(const float4*)(wr + kt * 32);
      float4 b = *(const float4*)(wr + kt * 32 + 4);
      bf16x8 f;
      f[0] = bfs(a.x); f[1] = bfs(a.y); f[2] = bfs(a.z); f[3] = bfs(a.w);
      f[4] = bfs(b.x); f[5] = bfs(b.y); f[6] = bfs(b.z); f[7] = bfs(b.w);
      bfr[nt][kt] = f;
    }
  }

  float wsv[4], qqv[4];
  #pragma unroll
  for (int nt = 0; nt < 4; ++nt) {
    wsv[nt] = ws_s[nt * 16 + l15];
    qqv[nt] = qqb_s[obase + nt * 16 + l15];
  }

  #pragma unroll
  for (int mt = 0; mt < 8; ++mt) {
    int row = mt * 16 + l15;
    int byte0 = (row << 7) + g * 16;
    int swz = (row & 7) << 4;
    bf16x8 a0 = *(const bf16x8*)(&Atile[(byte0) ^ swz]);
    bf16x8 a1 = *(const bf16x8*)(&Atile[(byte0 + 64) ^ swz]);
    f32x4 acc[4];
    #pragma unroll
    for (int nt = 0; nt < 4; ++nt) {
      acc[nt] = (f32x4){0.f, 0.f, 0.f, 0.f};
      acc[nt] = __builtin_amdgcn_mfma_f32_16x16x32_bf16(a0, bfr[nt][0], acc[nt], 0, 0, 0);
      acc[nt] = __builtin_amdgcn_mfma_f32_16x16x32_bf16(a1, bfr[nt][1], acc[nt], 0, 0, 0);
    }
    // score[n, wv] = sum_k ws[k] * tanh(keys + queries + bias)   (bs dropped: softmax-invariant)
    #pragma unroll
    for (int r = 0; r < 4; ++r) {
      float s = 0.f;
      #pragma unroll
      for (int nt = 0; nt < 4; ++nt) {
        float xg = acc[nt][r] + qqv[nt];
        float e = __expf(2.f * xg);                     // tanh(x) = 1 - 2/(e^(2x)+1)
        float th = 1.f - 2.f * __builtin_amdgcn_rcpf(e + 1.f);
        s = fmaf(wsv[nt], th, s);
      }
      s += __shfl_xor(s, 1);
      s += __shfl_xor(s, 2);
      s += __shfl_xor(s, 4);
      s += __shfl_xor(s, 8);
      if (l15 == 0) sc_s[mt * 16 + g * 4 + r][wv] = s;
    }
  }

  // ---------------- Phase D: softmax over n=127 (wave-local, head wv) ----
  {
    float s1 = sc_s[lane][wv];
    float s2 = (lane < 63) ? sc_s[64 + lane][wv] : -1e30f;
    float m = fmaxf(s1, s2);
    #pragma unroll
    for (int d = 1; d < 64; d <<= 1) m = fmaxf(m, __shfl_xor(m, d));
    float e1 = __expf(s1 - m);
    float e2 = (lane < 63) ? __expf(s2 - m) : 0.f;
    float sum = e1 + e2;
    #pragma unroll
    for (int d = 1; d < 64; d <<= 1) sum += __shfl_xor(sum, d);
    float inv = __builtin_amdgcn_rcpf(sum);
    wn_s[lane][wv] = e1 * inv;
    wn_s[64 + lane][wv] = e2 * inv;   // lane 63 -> wn_s[127] = 0 (pad row)
  }

  // ---------------- Phase E: values GEMM (kv part) + weighted reduce over n ----
  #pragma unroll
  for (int nt = 0; nt < 4; ++nt) {
    int o = obase + nt * 16 + l15;
    const float* wr = Wv + o * 128 + g * 8;   // kv part = cols 0..63
    #pragma unroll
    for (int kt = 0; kt < 2; ++kt) {
      float4 a = *(const float4*)(wr + kt * 32);
      float4 b = *(const float4*)(wr + kt * 32 + 4);
      bf16x8 f;
      f[0] = bfs(a.x); f[1] = bfs(a.y); f[2] = bfs(a.z); f[3] = bfs(a.w);
      f[4] = bfs(b.x); f[5] = bfs(b.y); f[6] = bfs(b.z); f[7] = bfs(b.w);
      bfr[nt][kt] = f;
    }
  }

  float cs[4] = {0.f, 0.f, 0.f, 0.f};
  #pragma unroll
  for (int mt = 0; mt < 8; ++mt) {
    int row = mt * 16 + l15;
    int byte0 = (row << 7) + g * 16;
    int swz = (row & 7) << 4;
    bf16x8 a0 = *(const bf16x8*)(&Atile[(byte0) ^ swz]);
    bf16x8 a1 = *(const bf16x8*)(&Atile[(byte0 + 64) ^ swz]);
    f32x4 vac[4];
    #pragma unroll
    for (int nt = 0; nt < 4; ++nt) {
      vac[nt] = (f32x4){0.f, 0.f, 0.f, 0.f};
      vac[nt] = __builtin_amdgcn_mfma_f32_16x16x32_bf16(a0, bfr[nt][0], vac[nt], 0, 0, 0);
      vac[nt] = __builtin_amdgcn_mfma_f32_16x16x32_bf16(a1, bfr[nt][1], vac[nt], 0, 0, 0);
    }
    #pragma unroll
    for (int r = 0; r < 4; ++r) {
      float wgt = wn_s[mt * 16 + g * 4 + r][wv];
      #pragma unroll
      for (int nt = 0; nt < 4; ++nt)
        cs[nt] = fmaf(vac[nt][r], wgt, cs[nt]);
    }
  }
  #pragma unroll
  for (int nt = 0; nt < 4; ++nt) {
    cs[nt] += __shfl_xor(cs[nt], 16);
    cs[nt] += __shfl_xor(cs[nt], 32);
  }
  if (g == 0) {
    #pragma unroll
    for (int nt = 0; nt < 4; ++nt) {
      int o = obase + nt * 16 + l15;
      out[bt * 256 + o] = cs[nt] + qv_s[o];
    }
  }
}

extern "C" void kernel_launch(void* const* d_in, const int* in_sizes, int n_in,
                              void* d_out, int out_size, void* d_ws, size_t ws_size,
                              hipStream_t stream) {
  const float* q_x  = (const float*)d_in[0];
  const float* kv_x = (const float*)d_in[1];
  const float* Wk   = (const float*)d_in[2];
  const float* Wq   = (const float*)d_in[3];
  const float* Wv   = (const float*)d_in[4];
  const float* bv   = (const float*)d_in[5];
  const float* bias = (const float*)d_in[6];
  const float* wsc  = (const float*)d_in[7];
  // d_in[8] = bs: constant across neighbors -> cancels in softmax, unused.
  float* out = (float*)d_out;

  rnn_attn_kernel<<<1024, 256, 0, stream>>>(q_x, kv_x, Wk, Wq, Wv, bv, bias, wsc, out);
}